// Round 2
// baseline (107.439 us; speedup 1.0000x reference)
//
#include <hip/hip_runtime.h>
#include <hip/hip_bf16.h>
#include <cfloat>

// DGG_StraightThrough: softmax over a singleton axis makes log_p == 0 exactly,
// so y == temp broadcast over batch. Output (stop_gradient trick) evaluates to:
//   non-topk: (0 - t) + t == +0.0 exactly
//   topk:     (1 - t) + t   (identical fp32 expression as reference)
// topk = top-8 per row of temp, ties -> lowest index (matches jax.lax.top_k).
//
// Structure: one wave per row (no LDS, no barriers in the hot path).
//   1) issue row loads (8 float4/lane, coalesced)
//   2) issue zero-fill stores (independent of loads -> overlapped)
//   3) in-register 8-pass argmax with __shfl_xor butterfly
//   4) one __syncthreads (drains stores) then lane0 patches 8x4 entries.

#define NROW 2048
#define KTOP 8
#define NB 4

__global__ __launch_bounds__(256) void dgg_fused_kernel(
    const float* __restrict__ temp, float* __restrict__ out)
{
    const int t = threadIdx.x;
    const int w = t >> 6;          // wave id within block (0..3)
    const int l = t & 63;          // lane
    const int row0 = blockIdx.x * 4;
    const int row  = row0 + w;     // this wave's row

    // ---- 1) issue this wave's row loads first (coalesced float4) ----
    const float4* row4 = (const float4*)(temp + (size_t)row * NROW);
    float4 f[8];
    #pragma unroll
    for (int i = 0; i < 8; ++i) f[i] = row4[l + 64 * i];   // float idx = 4*l + 256*i + c

    // ---- 2) zero-fill: block covers its 4 rows x 4 batches (coalesced) ----
    const float4 z = make_float4(0.f, 0.f, 0.f, 0.f);
    #pragma unroll
    for (int rr = 0; rr < 4; ++rr) {
        #pragma unroll
        for (int b = 0; b < NB; ++b) {
            float4* o4 = (float4*)(out + ((size_t)b * NROW + (row0 + rr)) * NROW);
            o4[t]       = z;
            o4[t + 256] = z;
        }
    }

    // ---- 3) per-wave top-8: 8 argmax passes, all in registers ----
    float sv[KTOP];
    int   si[KTOP];
    const int gbase = 4 * l;
    #pragma unroll
    for (int p = 0; p < KTOP; ++p) {
        float bv = -FLT_MAX;
        int   bi = 0x7fffffff;
        #pragma unroll
        for (int i = 0; i < 8; ++i) {
            { float v = f[i].x; int gi = gbase + 256*i + 0; if (v > bv || (v == bv && gi < bi)) { bv = v; bi = gi; } }
            { float v = f[i].y; int gi = gbase + 256*i + 1; if (v > bv || (v == bv && gi < bi)) { bv = v; bi = gi; } }
            { float v = f[i].z; int gi = gbase + 256*i + 2; if (v > bv || (v == bv && gi < bi)) { bv = v; bi = gi; } }
            { float v = f[i].w; int gi = gbase + 256*i + 3; if (v > bv || (v == bv && gi < bi)) { bv = v; bi = gi; } }
        }
        // 6-step butterfly: all 64 lanes converge to the row argmax
        #pragma unroll
        for (int m = 1; m < 64; m <<= 1) {
            float ov = __shfl_xor(bv, m);
            int   oi = __shfl_xor(bi, m);
            if (ov > bv || (ov == bv && oi < bi)) { bv = ov; bi = oi; }
        }
        sv[p] = bv;
        si[p] = bi;
        // clear the winner (exactly one lane owns it; mapping is bijective)
        const int s = bi - gbase;
        #pragma unroll
        for (int i = 0; i < 8; ++i) {
            if (s == 256*i + 0) f[i].x = -FLT_MAX;
            if (s == 256*i + 1) f[i].y = -FLT_MAX;
            if (s == 256*i + 2) f[i].z = -FLT_MAX;
            if (s == 256*i + 3) f[i].w = -FLT_MAX;
        }
    }

    // ---- 4) drain zero stores, then patch ----
    __syncthreads();   // emits s_waitcnt vmcnt(0) + s_barrier: zeros are durable

    if (l == 0) {
        #pragma unroll
        for (int p = 0; p < KTOP; ++p) {
            const float tv  = sv[p];
            const float val = (1.0f - tv) + tv;   // same fp32 expr as reference
            const int   idx = si[p];
            #pragma unroll
            for (int b = 0; b < NB; ++b)
                out[((size_t)b * NROW + row) * NROW + idx] = val;
        }
    }
}

extern "C" void kernel_launch(void* const* d_in, const int* in_sizes, int n_in,
                              void* d_out, int out_size, void* d_ws, size_t ws_size,
                              hipStream_t stream) {
    // inputs: 0:x  1:temp  2:W_proj  3:b_proj  4:W_dist  5:b_dist
    const float* temp = (const float*)d_in[1];
    float* out = (float*)d_out;
    dgg_fused_kernel<<<NROW / 4, 256, 0, stream>>>(temp, out);
}